// Round 6
// baseline (248.314 us; speedup 1.0000x reference)
//
#include <hip/hip_runtime.h>
#include <hip/hip_bf16.h>
#include <hip/hip_cooperative_groups.h>

namespace cg = cooperative_groups;

// Masked SDPA, flash-attention, transposed form (S^T = K*Q^T, O^T = V^T*P^T).
// R6: ONE cooperative launch. Phase 1: each of 256 blocks converts one 64-key
// K-tile + V-tile (fp32 -> bf16) into d_ws in MFMA-chunk order (R4 layout).
// grid.sync(). Phase 2: R4's proven main loop verbatim — async global_load_lds
// double-buffered KV tiles, ONE barrier per tile, per-lane-scalar online
// softmax, ds_bpermute P-transform, end merge of 2 kv-halves.

#define BZ 8
#define QL 2048
#define KLEN 2048
#define DH 128
#define KT 64
#define NTILES (KLEN / KT)  // 32
#define TCHUNKS 1024        // 16B chunks per 64-key tile per tensor

typedef float f32x4 __attribute__((ext_vector_type(4)));
typedef int   i32x4 __attribute__((ext_vector_type(4)));
typedef __bf16 bf16x8 __attribute__((ext_vector_type(8)));
typedef __bf16 bf16x4 __attribute__((ext_vector_type(4)));
typedef __bf16 bf16x2 __attribute__((ext_vector_type(2)));

#define QSC 0.12751879523298232f  // SCALE * log2(e); softmax in exp2 units
#define NEGV -1000000000.0f

__device__ __forceinline__ void gl2lds16(const void* g, void* l) {
  __builtin_amdgcn_global_load_lds((const __attribute__((address_space(1))) void*)g,
                                   (__attribute__((address_space(3))) void*)l, 16, 0, 0);
}
__device__ __forceinline__ float bperm(int srclane4, float v) {
  return __int_as_float(__builtin_amdgcn_ds_bpermute(srclane4, __float_as_int(v)));
}

// ---------------------------------------------------------------------------
// Cooperative kernel: grid 256 x 512 thr, 64 KiB LDS (1 block/CU, co-resident).
// ---------------------------------------------------------------------------
__global__ __launch_bounds__(512, 1) void fattn_coop(
    const float* __restrict__ kg, const float* __restrict__ vg,
    __bf16* __restrict__ khat, __bf16* __restrict__ vhat,
    const float* __restrict__ qg_, const int* __restrict__ maskg,
    float* __restrict__ outg) {
  __shared__ __align__(16) __bf16 smem[2][2][TCHUNKS * 8];  // 64 KiB

  const int tid = threadIdx.x;
  const int bid = blockIdx.x;

  // ============ Phase 1: prep tile (pb, pt) = (bid>>5, bid&31) ============
  // K-hat chunk g: kc = g>>6, key = (g&63) ^ ((kc&3)<<2);
  //   data = K[pb][pt*64+key][kc*8 + j], j=0..7  (16B, coalesced store)
  // V-hat chunk g: vc = g>>7, d = (g&127) ^ ((vc&3)<<2);
  //   data[j] = V[pb][pt*64 + vc*8 + j][d]
  {
    const int pb = bid >> 5, pt = bid & 31;
    const float* ksrc = kg + ((size_t)(pb * KLEN + pt * 64)) * DH;
    const float* vsrc = vg + ((size_t)(pb * KLEN + pt * 64)) * DH;
    __bf16* kdst = khat + (size_t)bid * TCHUNKS * 8;
    __bf16* vdst = vhat + (size_t)bid * TCHUNKS * 8;
#pragma unroll
    for (int i = 0; i < 2; ++i) {
      const int g = i * 512 + tid;
      const int kc = g >> 6;
      const int key = (g & 63) ^ ((kc & 3) << 2);
      const float* s = ksrc + (size_t)key * DH + kc * 8;
      f32x4 a = *(const f32x4*)s;
      f32x4 d4 = *(const f32x4*)(s + 4);
      bf16x8 w;
      w[0]=(__bf16)a[0]; w[1]=(__bf16)a[1]; w[2]=(__bf16)a[2]; w[3]=(__bf16)a[3];
      w[4]=(__bf16)d4[0]; w[5]=(__bf16)d4[1]; w[6]=(__bf16)d4[2]; w[7]=(__bf16)d4[3];
      *(bf16x8*)&kdst[(size_t)g * 8] = w;
    }
#pragma unroll
    for (int i = 0; i < 2; ++i) {
      const int g = i * 512 + tid;
      const int vc = g >> 7;
      const int d = (g & 127) ^ ((vc & 3) << 2);
      bf16x8 w;
#pragma unroll
      for (int j = 0; j < 8; ++j) w[j] = (__bf16)vsrc[(size_t)(vc * 8 + j) * DH + d];
      *(bf16x8*)&vdst[(size_t)g * 8] = w;
    }
  }
  __threadfence();
  cg::this_grid().sync();
  __threadfence();

  // ============ Phase 2: attention (R4 fattn2, verbatim) ==================
  const int wv = tid >> 6, ln = tid & 63;
  const int qd = ln >> 4, lc = ln & 15;
  const int ab = bid & 7, qt = bid >> 3;   // XCD-L2 locality: batch = bid&7
  const int q0 = qt * 64, wq = wv & 3, h = wv >> 2;

  // Q fragment (B-operand for S^T): lane holds Q[q0+wq*16+lc][kf*32+qd*8+j]*QSC
  bf16x8 qf[4];
  {
    const float* qr = qg_ + ((size_t)(ab * QL + q0 + wq * 16 + lc)) * DH + qd * 8;
#pragma unroll
    for (int kf = 0; kf < 4; ++kf) {
      f32x4 a = *(const f32x4*)(qr + kf * 32);
      f32x4 c = *(const f32x4*)(qr + kf * 32 + 4);
      bf16x8 t;
      t[0]=(__bf16)(a[0]*QSC); t[1]=(__bf16)(a[1]*QSC); t[2]=(__bf16)(a[2]*QSC); t[3]=(__bf16)(a[3]*QSC);
      t[4]=(__bf16)(c[0]*QSC); t[5]=(__bf16)(c[1]*QSC); t[6]=(__bf16)(c[2]*QSC); t[7]=(__bf16)(c[3]*QSC);
      qf[kf] = t;
    }
  }

  const __bf16* Kb = khat + (size_t)ab * NTILES * TCHUNKS * 8;
  const __bf16* Vb = vhat + (size_t)ab * NTILES * TCHUNKS * 8;
  const int* mrow = maskg + ab * KLEN;

  auto stage = [&](int t, int buf) {
    const __bf16* kt = Kb + (size_t)t * TCHUNKS * 8;
    const __bf16* vt = Vb + (size_t)t * TCHUNKS * 8;
    const int c0 = (wv * 2) * 64;        // wave-uniform chunk base, lane adds ln*16B
    const int c1 = (wv * 2 + 1) * 64;
    gl2lds16(kt + (size_t)(c0 + ln) * 8, &smem[0][buf][c0 * 8]);
    gl2lds16(kt + (size_t)(c1 + ln) * 8, &smem[0][buf][c1 * 8]);
    gl2lds16(vt + (size_t)(c0 + ln) * 8, &smem[1][buf][c0 * 8]);
    gl2lds16(vt + (size_t)(c1 + ln) * 8, &smem[1][buf][c1 * 8]);
  };

  f32x4 oacc[8];
#pragma unroll
  for (int i = 0; i < 8; ++i) oacc[i] = (f32x4){0.f, 0.f, 0.f, 0.f};
  float mi = -INFINITY, li = 0.f;        // per-lane scalars (q-row = lc)

  stage(0, 0);
  i32x4 mc0 = *(const i32x4*)&mrow[h * 32 + qd * 4];
  i32x4 mc1 = *(const i32x4*)&mrow[h * 32 + 16 + qd * 4];
  i32x4 mn0 = {}, mn1 = {};

  for (int t = 0; t < NTILES; ++t) {
    __syncthreads();                     // drains stage(t); syncs buffers
    const bool more = (t + 1 < NTILES);
    if (more) {
      mn0 = *(const i32x4*)&mrow[(t + 1) * KT + h * 32 + qd * 4];
      mn1 = *(const i32x4*)&mrow[(t + 1) * KT + h * 32 + 16 + qd * 4];
      stage(t + 1, (t + 1) & 1);         // flies across the whole compute below
    }

    const __bf16* cK = smem[0][t & 1];
    const __bf16* cV = smem[1][t & 1];

    // ---- S^T = K * (Q*QSC)^T : 2 key-frags (f = h*2, h*2+1), 4 k-steps ----
    f32x4 sa0 = (f32x4){0.f, 0.f, 0.f, 0.f};
    f32x4 sa1 = (f32x4){0.f, 0.f, 0.f, 0.f};
    const int sw = qd << 2;
#pragma unroll
    for (int kf = 0; kf < 4; ++kf) {
      const int kc = kf * 4 + qd;
      bf16x8 k0 = *(const bf16x8*)&cK[(kc * 64 + (((h * 2) * 16 + lc) ^ sw)) * 8];
      bf16x8 k1 = *(const bf16x8*)&cK[(kc * 64 + (((h * 2 + 1) * 16 + lc) ^ sw)) * 8];
      sa0 = __builtin_amdgcn_mfma_f32_16x16x32_bf16(k0, qf[kf], sa0, 0, 0, 0);
      sa1 = __builtin_amdgcn_mfma_f32_16x16x32_bf16(k1, qf[kf], sa1, 0, 0, 0);
    }

    // ---- key-padding mask (C rows = keys = qd*4+r) ----
#pragma unroll
    for (int r = 0; r < 4; ++r) {
      sa0[r] = mc0[r] ? sa0[r] : NEGV;
      sa1[r] = mc1[r] ? sa1[r] : NEGV;
    }

    // ---- online softmax: per-lane scalar state for q-row lc ----
    float rm = sa0[0];
#pragma unroll
    for (int r = 1; r < 4; ++r) rm = fmaxf(rm, sa0[r]);
#pragma unroll
    for (int r = 0; r < 4; ++r) rm = fmaxf(rm, sa1[r]);
    rm = fmaxf(rm, __shfl_xor(rm, 16, 64));
    rm = fmaxf(rm, __shfl_xor(rm, 32, 64));
    const float mn = fmaxf(mi, rm);
    const float alpha = __builtin_amdgcn_exp2f(mi - mn);
    mi = mn;
    float rs = 0.f;
#pragma unroll
    for (int r = 0; r < 4; ++r) {
      sa0[r] = __builtin_amdgcn_exp2f(sa0[r] - mn); rs += sa0[r];
      sa1[r] = __builtin_amdgcn_exp2f(sa1[r] - mn); rs += sa1[r];
    }
    rs += __shfl_xor(rs, 16, 64);
    rs += __shfl_xor(rs, 32, 64);
    li = li * alpha + rs;

    // ---- P^T C-layout -> B-layout via ds_bpermute ----
    const int a0 = ((((qd & 1) * 2) * 16) + lc) * 4;
    const int a1 = a0 + 64;
    float tv[8];
#pragma unroll
    for (int r = 0; r < 4; ++r) {
      float x00 = bperm(a0, sa0[r]), x10 = bperm(a0, sa1[r]);
      float x01 = bperm(a1, sa0[r]), x11 = bperm(a1, sa1[r]);
      tv[r]     = (qd < 2) ? x00 : x10;
      tv[4 + r] = (qd < 2) ? x01 : x11;
    }
    bf16x8 pf;
#pragma unroll
    for (int j = 0; j < 8; ++j) pf[j] = (__bf16)tv[j];

    // ---- O^T rescale + O^T += V^T * P^T ----
#pragma unroll
    for (int nt = 0; nt < 8; ++nt)
#pragma unroll
      for (int r = 0; r < 4; ++r) oacc[nt][r] *= alpha;
    const int vcc = h * 4 + qd;
#pragma unroll
    for (int nt = 0; nt < 8; ++nt) {
      bf16x8 vf = *(const bf16x8*)&cV[(vcc * 128 + ((nt * 16 + lc) ^ sw)) * 8];
      oacc[nt] = __builtin_amdgcn_mfma_f32_16x16x32_bf16(vf, pf, oacc[nt], 0, 0, 0);
    }

    if (more) { mc0 = mn0; mc1 = mn1; }
  }

  // ---- merge the two kv-halves (waves h=1 publish, h=0 combine+store) ----
  __syncthreads();
  float* fb = (float*)&smem[0][0][0];    // 64 KiB scratch; 2304 floats per wq
  if (h == 1) {
    float* mb = fb + wq * 2304;
#pragma unroll
    for (int nt = 0; nt < 8; ++nt)
      *(f32x4*)&mb[(nt * 64 + ln) * 4] = oacc[nt];
    mb[2048 + ln * 2] = mi;
    mb[2048 + ln * 2 + 1] = li;
  }
  __syncthreads();
  if (h == 0) {
    const float* pb = fb + wq * 2304;
    const float m2 = pb[2048 + ln * 2], l2 = pb[2048 + ln * 2 + 1];
    const float M = fmaxf(mi, m2);
    const float w1 = __builtin_amdgcn_exp2f(mi - M);
    const float w2 = __builtin_amdgcn_exp2f(m2 - M);
    const float invL = 1.0f / (w1 * li + w2 * l2);
    float* orow = outg + ((size_t)(ab * QL + q0 + wq * 16 + lc)) * DH;
#pragma unroll
    for (int nt = 0; nt < 8; ++nt) {
      f32x4 o2 = *(const f32x4*)&pb[(nt * 64 + ln) * 4];
      f32x4 res;
#pragma unroll
      for (int r = 0; r < 4; ++r) res[r] = (w1 * oacc[nt][r] + w2 * o2[r]) * invL;
      *(f32x4*)&orow[nt * 16 + qd * 4] = res;
    }
  }
}

// ---------------------------------------------------------------------------
// Fallback single-pass kernel (R2, proven) — used only if ws is too small.
// ---------------------------------------------------------------------------
#define KPITCH 136
#define VPITCH 72
#define PPITCH 72

__global__ __launch_bounds__(256, 1) void fattn_mono(
    const float* __restrict__ qgp, const float* __restrict__ kg,
    const float* __restrict__ vg, const int* __restrict__ maskg,
    float* __restrict__ outg) {
  __shared__ __bf16 sK[KT][KPITCH];
  __shared__ __bf16 sVT[DH][VPITCH];
  __shared__ __bf16 sP[4][16][PPITCH];

  const int tid = threadIdx.x;
  const int wv = tid >> 6, ln = tid & 63;
  const int qd = ln >> 4, lc = ln & 15;
  const int bid = blockIdx.x;
  const int b = bid >> 5;
  const int q0 = (bid & 31) << 6;
  const int qw = q0 + (wv << 4);

  bf16x8 qf[4];
  {
    const float* qr = qgp + ((size_t)(b * QL + qw + lc)) * DH + qd * 8;
#pragma unroll
    for (int kf = 0; kf < 4; ++kf) {
      f32x4 a = *(const f32x4*)(qr + kf * 32);
      f32x4 c = *(const f32x4*)(qr + kf * 32 + 4);
      bf16x8 t;
      t[0]=(__bf16)(a[0]*QSC); t[1]=(__bf16)(a[1]*QSC); t[2]=(__bf16)(a[2]*QSC); t[3]=(__bf16)(a[3]*QSC);
      t[4]=(__bf16)(c[0]*QSC); t[5]=(__bf16)(c[1]*QSC); t[6]=(__bf16)(c[2]*QSC); t[7]=(__bf16)(c[3]*QSC);
      qf[kf] = t;
    }
  }

  const float* kb = kg + (size_t)b * KLEN * DH;
  const float* vb = vg + (size_t)b * KLEN * DH;
  const int* mrow = maskg + b * KLEN;

  f32x4 kreg[8], va[4], vbr[4];

  auto load_tile = [&](int t) {
    const float* kt = kb + ((size_t)t * KT) * DH;
#pragma unroll
    for (int it = 0; it < 8; ++it) {
      int f = it * 256 + tid;
      kreg[it] = *(const f32x4*)(kt + (size_t)(f >> 5) * DH + (f & 31) * 4);
    }
    const float* vt = vb + ((size_t)t * KT) * DH;
#pragma unroll
    for (int it = 0; it < 4; ++it) {
      int u = it * 256 + tid;
      int m = u & 31, dc = (u >> 5) * 4;
      va[it]  = *(const f32x4*)(vt + (size_t)(2 * m) * DH + dc);
      vbr[it] = *(const f32x4*)(vt + (size_t)(2 * m + 1) * DH + dc);
    }
  };
  auto store_tile = [&]() {
#pragma unroll
    for (int it = 0; it < 8; ++it) {
      int f = it * 256 + tid;
      bf16x4 w;
      w[0]=(__bf16)kreg[it][0]; w[1]=(__bf16)kreg[it][1];
      w[2]=(__bf16)kreg[it][2]; w[3]=(__bf16)kreg[it][3];
      *(bf16x4*)&sK[f >> 5][(f & 31) * 4] = w;
    }
#pragma unroll
    for (int it = 0; it < 4; ++it) {
      int u = it * 256 + tid;
      int m = u & 31, dc = (u >> 5) * 4;
#pragma unroll
      for (int j = 0; j < 4; ++j) {
        bf16x2 p2;
        p2[0] = (__bf16)va[it][j];
        p2[1] = (__bf16)vbr[it][j];
        *(bf16x2*)&sVT[dc + j][2 * m] = p2;
      }
    }
  };

  f32x4 oacc[8];
#pragma unroll
  for (int i = 0; i < 8; ++i) oacc[i] = (f32x4){0.f, 0.f, 0.f, 0.f};
  float mi[4] = {-INFINITY, -INFINITY, -INFINITY, -INFINITY};
  float li[4] = {0.f, 0.f, 0.f, 0.f};

  load_tile(0); store_tile(); __syncthreads();

  for (int t = 0; t < (KLEN / KT); ++t) {
    const bool more = (t + 1 < (KLEN / KT));
    if (more) load_tile(t + 1);

    f32x4 sa[4];
#pragma unroll
    for (int f = 0; f < 4; ++f) sa[f] = (f32x4){0.f, 0.f, 0.f, 0.f};
#pragma unroll
    for (int kf = 0; kf < 4; ++kf)
#pragma unroll
      for (int f = 0; f < 4; ++f) {
        bf16x8 bk = *(const bf16x8*)&sK[f * 16 + lc][kf * 32 + qd * 8];
        sa[f] = __builtin_amdgcn_mfma_f32_16x16x32_bf16(qf[kf], bk, sa[f], 0, 0, 0);
      }

    const int kv0 = t * KT;
#pragma unroll
    for (int f = 0; f < 4; ++f) {
      const bool keep = mrow[kv0 + f * 16 + lc] != 0;
#pragma unroll
      for (int r = 0; r < 4; ++r) sa[f][r] = keep ? sa[f][r] : NEGV;
    }

    float rm[4], alpha[4], rs[4];
#pragma unroll
    for (int r = 0; r < 4; ++r)
      rm[r] = fmaxf(fmaxf(sa[0][r], sa[1][r]), fmaxf(sa[2][r], sa[3][r]));
#pragma unroll
    for (int sh = 0; sh < 4; ++sh) {
      const int off = 1 << sh;
#pragma unroll
      for (int r = 0; r < 4; ++r) rm[r] = fmaxf(rm[r], __shfl_xor(rm[r], off, 64));
    }
#pragma unroll
    for (int r = 0; r < 4; ++r) {
      float mn = fmaxf(mi[r], rm[r]);
      alpha[r] = __builtin_amdgcn_exp2f(mi[r] - mn);
      mi[r] = mn; rs[r] = 0.f;
    }
#pragma unroll
    for (int f = 0; f < 4; ++f)
#pragma unroll
      for (int r = 0; r < 4; ++r) {
        float p = __builtin_amdgcn_exp2f(sa[f][r] - mi[r]);
        sa[f][r] = p; rs[r] += p;
      }
#pragma unroll
    for (int sh = 0; sh < 4; ++sh) {
      const int off = 1 << sh;
#pragma unroll
      for (int r = 0; r < 4; ++r) rs[r] += __shfl_xor(rs[r], off, 64);
    }
#pragma unroll
    for (int r = 0; r < 4; ++r) li[r] = li[r] * alpha[r] + rs[r];

#pragma unroll
    for (int f = 0; f < 4; ++f)
#pragma unroll
      for (int r = 0; r < 4; ++r)
        sP[wv][qd * 4 + r][f * 16 + lc] = (__bf16)sa[f][r];
#pragma unroll
    for (int nt = 0; nt < 8; ++nt)
#pragma unroll
      for (int r = 0; r < 4; ++r) oacc[nt][r] *= alpha[r];

#pragma unroll
    for (int kp = 0; kp < 2; ++kp) {
      bf16x8 ap = *(const bf16x8*)&sP[wv][lc][kp * 32 + qd * 8];
#pragma unroll
      for (int nt = 0; nt < 8; ++nt) {
        bf16x8 bv = *(const bf16x8*)&sVT[nt * 16 + lc][kp * 32 + qd * 8];
        oacc[nt] = __builtin_amdgcn_mfma_f32_16x16x32_bf16(ap, bv, oacc[nt], 0, 0, 0);
      }
    }

    __syncthreads();
    if (more) store_tile();
    __syncthreads();
  }

  float inv[4];
#pragma unroll
  for (int r = 0; r < 4; ++r) inv[r] = 1.0f / li[r];
  float* orow = outg + ((size_t)(b * QL + qw)) * DH;
#pragma unroll
  for (int nt = 0; nt < 8; ++nt)
#pragma unroll
    for (int r = 0; r < 4; ++r)
      orow[(size_t)(qd * 4 + r) * DH + nt * 16 + lc] = oacc[nt][r] * inv[r];
}

extern "C" void kernel_launch(void* const* d_in, const int* in_sizes, int n_in,
                              void* d_out, int out_size, void* d_ws, size_t ws_size,
                              hipStream_t stream) {
  (void)in_sizes; (void)n_in; (void)out_size;
  const float* q = (const float*)d_in[0];
  const float* k = (const float*)d_in[1];
  const float* v = (const float*)d_in[2];
  const int* mask = (const int*)d_in[3];
  float* out = (float*)d_out;

  const size_t kv_elems = (size_t)BZ * KLEN * DH;  // per tensor (4 MiB as bf16)
  if (ws_size >= 2 * kv_elems * sizeof(__bf16)) {
    __bf16* khat = (__bf16*)d_ws;
    __bf16* vhat = khat + kv_elems;
    void* args[] = {(void*)&k, (void*)&v, (void*)&khat, (void*)&vhat,
                    (void*)&q, (void*)&mask, (void*)&out};
    hipLaunchCooperativeKernel((const void*)fattn_coop, dim3(256), dim3(512),
                               args, 0, stream);
  } else {
    fattn_mono<<<dim3(BZ * (QL / 64)), dim3(256), 0, stream>>>(q, k, v, mask, out);
  }
}

// Round 7
// 130.366 us; speedup vs baseline: 1.9047x; 1.9047x over previous
//
#include <hip/hip_runtime.h>
#include <hip/hip_bf16.h>

// Masked SDPA, flash-attention, transposed form (S^T = K*Q^T, O^T = V^T*P^T).
// R7: R4's proven structure, re-gridded for 2 co-resident blocks/CU:
//   - fused prep kernel (fp32 KV -> bf16 in MFMA-chunk order, XOR-swizzled)
//   - main: 512 blocks x 256 thr (4 waves = 2 q-subtiles x 2 kv-halves),
//     32 q-rows/block, full KV sweep, 64 KiB dbuf LDS -> 2 blocks/CU so the
//     per-tile barrier drains of the two blocks anti-phase.
// K-loop semantics byte-identical to R4 (async global_load_lds, 1 barrier/tile,
// per-lane-scalar online softmax, ds_bpermute P-transform, end merge of halves).

#define BZ 8
#define QL 2048
#define KLEN 2048
#define DH 128
#define KT 64
#define NTILES (KLEN / KT)  // 32
#define TCHUNKS 1024        // 16B chunks per 64-key tile per tensor

typedef float f32x4 __attribute__((ext_vector_type(4)));
typedef int   i32x4 __attribute__((ext_vector_type(4)));
typedef __bf16 bf16x8 __attribute__((ext_vector_type(8)));
typedef __bf16 bf16x4 __attribute__((ext_vector_type(4)));
typedef __bf16 bf16x2 __attribute__((ext_vector_type(2)));

#define QSC 0.12751879523298232f  // SCALE * log2(e); softmax in exp2 units
#define NEGV -1000000000.0f

__device__ __forceinline__ void gl2lds16(const void* g, void* l) {
  __builtin_amdgcn_global_load_lds((const __attribute__((address_space(1))) void*)g,
                                   (__attribute__((address_space(3))) void*)l, 16, 0, 0);
}
__device__ __forceinline__ float bperm(int srclane4, float v) {
  return __int_as_float(__builtin_amdgcn_ds_bpermute(srclane4, __float_as_int(v)));
}

// ---------------------------------------------------------------------------
// Fused prep (R6 phase-1, correctness-proven): 256 blocks x 512 thr.
// Block bid handles tile (pb, pt) = (bid>>5, bid&31).
// K-hat chunk g: kc=g>>6, key=(g&63)^((kc&3)<<2); data K[key][kc*8+j]
// V-hat chunk g: vc=g>>7, d=(g&127)^((vc&3)<<2); data[j]=V[vc*8+j][d]
// ---------------------------------------------------------------------------
__global__ void prep_kv(const float* __restrict__ kg, const float* __restrict__ vg,
                        __bf16* __restrict__ khat, __bf16* __restrict__ vhat) {
  const int tid = threadIdx.x;
  const int bid = blockIdx.x;
  const int pb = bid >> 5, pt = bid & 31;
  const float* ksrc = kg + ((size_t)(pb * KLEN + pt * 64)) * DH;
  const float* vsrc = vg + ((size_t)(pb * KLEN + pt * 64)) * DH;
  __bf16* kdst = khat + (size_t)bid * TCHUNKS * 8;
  __bf16* vdst = vhat + (size_t)bid * TCHUNKS * 8;
#pragma unroll
  for (int i = 0; i < 2; ++i) {
    const int g = i * 512 + tid;
    const int kc = g >> 6;
    const int key = (g & 63) ^ ((kc & 3) << 2);
    const float* s = ksrc + (size_t)key * DH + kc * 8;
    f32x4 a = *(const f32x4*)s;
    f32x4 d4 = *(const f32x4*)(s + 4);
    bf16x8 w;
    w[0]=(__bf16)a[0]; w[1]=(__bf16)a[1]; w[2]=(__bf16)a[2]; w[3]=(__bf16)a[3];
    w[4]=(__bf16)d4[0]; w[5]=(__bf16)d4[1]; w[6]=(__bf16)d4[2]; w[7]=(__bf16)d4[3];
    *(bf16x8*)&kdst[(size_t)g * 8] = w;
  }
#pragma unroll
  for (int i = 0; i < 2; ++i) {
    const int g = i * 512 + tid;
    const int vc = g >> 7;
    const int d = (g & 127) ^ ((vc & 3) << 2);
    bf16x8 w;
#pragma unroll
    for (int j = 0; j < 8; ++j) w[j] = (__bf16)vsrc[(size_t)(vc * 8 + j) * DH + d];
    *(bf16x8*)&vdst[(size_t)g * 8] = w;
  }
}

// ---------------------------------------------------------------------------
// Main kernel. Grid 512 (b = bid&7 XCD-L2 locality; qt = bid>>3 -> 32 q-rows),
// 256 thr = 4 waves. wq = wv&1 (q-subtile of 16 rows), h = wv>>1 (kv-half).
// 64 KiB LDS -> 2 blocks/CU.
// ---------------------------------------------------------------------------
__global__ __launch_bounds__(256, 2) void fattn4(
    const __bf16* __restrict__ khat, const __bf16* __restrict__ vhat,
    const float* __restrict__ qg_, const int* __restrict__ maskg,
    float* __restrict__ outg) {
  __shared__ __align__(16) __bf16 smem[2][2][TCHUNKS * 8];  // [K/V][buf] 64 KiB

  const int tid = threadIdx.x;
  const int wv = tid >> 6, ln = tid & 63;
  const int qd = ln >> 4, lc = ln & 15;
  const int ab = blockIdx.x & 7, qt = blockIdx.x >> 3;
  const int q0 = qt * 32, wq = wv & 1, h = wv >> 1;

  // Q fragment (B-operand for S^T): lane holds Q[q0+wq*16+lc][kf*32+qd*8+j]*QSC
  bf16x8 qf[4];
  {
    const float* qr = qg_ + ((size_t)(ab * QL + q0 + wq * 16 + lc)) * DH + qd * 8;
#pragma unroll
    for (int kf = 0; kf < 4; ++kf) {
      f32x4 a = *(const f32x4*)(qr + kf * 32);
      f32x4 c = *(const f32x4*)(qr + kf * 32 + 4);
      bf16x8 t;
      t[0]=(__bf16)(a[0]*QSC); t[1]=(__bf16)(a[1]*QSC); t[2]=(__bf16)(a[2]*QSC); t[3]=(__bf16)(a[3]*QSC);
      t[4]=(__bf16)(c[0]*QSC); t[5]=(__bf16)(c[1]*QSC); t[6]=(__bf16)(c[2]*QSC); t[7]=(__bf16)(c[3]*QSC);
      qf[kf] = t;
    }
  }

  const __bf16* Kb = khat + (size_t)ab * NTILES * TCHUNKS * 8;
  const __bf16* Vb = vhat + (size_t)ab * NTILES * TCHUNKS * 8;
  const int* mrow = maskg + ab * KLEN;

  // async stage of tile t: 4 waves x 4 instr x 64 lanes = 1024 chunks / tensor
  auto stage = [&](int t, int buf) {
    const __bf16* kt = Kb + (size_t)t * TCHUNKS * 8;
    const __bf16* vt = Vb + (size_t)t * TCHUNKS * 8;
#pragma unroll
    for (int i = 0; i < 4; ++i) {
      const int c = (wv * 4 + i) * 64;   // wave-uniform base, lane adds ln*16B
      gl2lds16(kt + (size_t)(c + ln) * 8, &smem[0][buf][c * 8]);
      gl2lds16(vt + (size_t)(c + ln) * 8, &smem[1][buf][c * 8]);
    }
  };

  f32x4 oacc[8];
#pragma unroll
  for (int i = 0; i < 8; ++i) oacc[i] = (f32x4){0.f, 0.f, 0.f, 0.f};
  float mi = -INFINITY, li = 0.f;        // per-lane scalars (q-row = lc)

  stage(0, 0);
  i32x4 mc0 = *(const i32x4*)&mrow[h * 32 + qd * 4];
  i32x4 mc1 = *(const i32x4*)&mrow[h * 32 + 16 + qd * 4];
  i32x4 mn0 = {}, mn1 = {};

  for (int t = 0; t < NTILES; ++t) {
    __syncthreads();                     // drains stage(t); syncs buffers
    const bool more = (t + 1 < NTILES);
    if (more) {
      mn0 = *(const i32x4*)&mrow[(t + 1) * KT + h * 32 + qd * 4];
      mn1 = *(const i32x4*)&mrow[(t + 1) * KT + h * 32 + 16 + qd * 4];
      stage(t + 1, (t + 1) & 1);         // flies across the whole compute below
    }

    const __bf16* cK = smem[0][t & 1];
    const __bf16* cV = smem[1][t & 1];

    // ---- S^T = K * (Q*QSC)^T : 2 key-frags (f = h*2, h*2+1), 4 k-steps ----
    f32x4 sa0 = (f32x4){0.f, 0.f, 0.f, 0.f};
    f32x4 sa1 = (f32x4){0.f, 0.f, 0.f, 0.f};
    const int sw = qd << 2;
#pragma unroll
    for (int kf = 0; kf < 4; ++kf) {
      const int kc = kf * 4 + qd;
      bf16x8 k0 = *(const bf16x8*)&cK[(kc * 64 + (((h * 2) * 16 + lc) ^ sw)) * 8];
      bf16x8 k1 = *(const bf16x8*)&cK[(kc * 64 + (((h * 2 + 1) * 16 + lc) ^ sw)) * 8];
      sa0 = __builtin_amdgcn_mfma_f32_16x16x32_bf16(k0, qf[kf], sa0, 0, 0, 0);
      sa1 = __builtin_amdgcn_mfma_f32_16x16x32_bf16(k1, qf[kf], sa1, 0, 0, 0);
    }

    // ---- key-padding mask (C rows = keys = qd*4+r) ----
#pragma unroll
    for (int r = 0; r < 4; ++r) {
      sa0[r] = mc0[r] ? sa0[r] : NEGV;
      sa1[r] = mc1[r] ? sa1[r] : NEGV;
    }

    // ---- online softmax: per-lane scalar state for q-row lc ----
    float rm = sa0[0];
#pragma unroll
    for (int r = 1; r < 4; ++r) rm = fmaxf(rm, sa0[r]);
#pragma unroll
    for (int r = 0; r < 4; ++r) rm = fmaxf(rm, sa1[r]);
    rm = fmaxf(rm, __shfl_xor(rm, 16, 64));
    rm = fmaxf(rm, __shfl_xor(rm, 32, 64));
    const float mn = fmaxf(mi, rm);
    const float alpha = __builtin_amdgcn_exp2f(mi - mn);
    mi = mn;
    float rs = 0.f;
#pragma unroll
    for (int r = 0; r < 4; ++r) {
      sa0[r] = __builtin_amdgcn_exp2f(sa0[r] - mn); rs += sa0[r];
      sa1[r] = __builtin_amdgcn_exp2f(sa1[r] - mn); rs += sa1[r];
    }
    rs += __shfl_xor(rs, 16, 64);
    rs += __shfl_xor(rs, 32, 64);
    li = li * alpha + rs;

    // ---- P^T C-layout -> B-layout via ds_bpermute ----
    const int a0 = ((((qd & 1) * 2) * 16) + lc) * 4;
    const int a1 = a0 + 64;
    float tv[8];
#pragma unroll
    for (int r = 0; r < 4; ++r) {
      float x00 = bperm(a0, sa0[r]), x10 = bperm(a0, sa1[r]);
      float x01 = bperm(a1, sa0[r]), x11 = bperm(a1, sa1[r]);
      tv[r]     = (qd < 2) ? x00 : x10;
      tv[4 + r] = (qd < 2) ? x01 : x11;
    }
    bf16x8 pf;
#pragma unroll
    for (int j = 0; j < 8; ++j) pf[j] = (__bf16)tv[j];

    // ---- O^T rescale + O^T += V^T * P^T ----
#pragma unroll
    for (int nt = 0; nt < 8; ++nt)
#pragma unroll
      for (int r = 0; r < 4; ++r) oacc[nt][r] *= alpha;
    const int vcc = h * 4 + qd;
#pragma unroll
    for (int nt = 0; nt < 8; ++nt) {
      bf16x8 vf = *(const bf16x8*)&cV[(vcc * 128 + ((nt * 16 + lc) ^ sw)) * 8];
      oacc[nt] = __builtin_amdgcn_mfma_f32_16x16x32_bf16(vf, pf, oacc[nt], 0, 0, 0);
    }

    if (more) { mc0 = mn0; mc1 = mn1; }
  }

  // ---- merge the two kv-halves (waves h=1 publish, h=0 combine+store) ----
  __syncthreads();
  float* fb = (float*)&smem[0][0][0];    // scratch; 2304 floats per wq
  if (h == 1) {
    float* mb = fb + wq * 2304;
#pragma unroll
    for (int nt = 0; nt < 8; ++nt)
      *(f32x4*)&mb[(nt * 64 + ln) * 4] = oacc[nt];
    mb[2048 + ln * 2] = mi;
    mb[2048 + ln * 2 + 1] = li;
  }
  __syncthreads();
  if (h == 0) {
    const float* pb = fb + wq * 2304;
    const float m2 = pb[2048 + ln * 2], l2 = pb[2048 + ln * 2 + 1];
    const float M = fmaxf(mi, m2);
    const float w1 = __builtin_amdgcn_exp2f(mi - M);
    const float w2 = __builtin_amdgcn_exp2f(m2 - M);
    const float invL = 1.0f / (w1 * li + w2 * l2);
    float* orow = outg + ((size_t)(ab * QL + q0 + wq * 16 + lc)) * DH;
#pragma unroll
    for (int nt = 0; nt < 8; ++nt) {
      f32x4 o2 = *(const f32x4*)&pb[(nt * 64 + ln) * 4];
      f32x4 res;
#pragma unroll
      for (int r = 0; r < 4; ++r) res[r] = (w1 * oacc[nt][r] + w2 * o2[r]) * invL;
      *(f32x4*)&orow[nt * 16 + qd * 4] = res;
    }
  }
}

// ---------------------------------------------------------------------------
// Fallback single-pass kernel (R2, proven) — used only if ws is too small.
// ---------------------------------------------------------------------------
#define KPITCH 136
#define VPITCH 72
#define PPITCH 72

__global__ __launch_bounds__(256, 1) void fattn_mono(
    const float* __restrict__ qgp, const float* __restrict__ kg,
    const float* __restrict__ vg, const int* __restrict__ maskg,
    float* __restrict__ outg) {
  __shared__ __bf16 sK[KT][KPITCH];
  __shared__ __bf16 sVT[DH][VPITCH];
  __shared__ __bf16 sP[4][16][PPITCH];

  const int tid = threadIdx.x;
  const int wv = tid >> 6, ln = tid & 63;
  const int qd = ln >> 4, lc = ln & 15;
  const int bid = blockIdx.x;
  const int b = bid >> 5;
  const int q0 = (bid & 31) << 6;
  const int qw = q0 + (wv << 4);

  bf16x8 qf[4];
  {
    const float* qr = qgp + ((size_t)(b * QL + qw + lc)) * DH + qd * 8;
#pragma unroll
    for (int kf = 0; kf < 4; ++kf) {
      f32x4 a = *(const f32x4*)(qr + kf * 32);
      f32x4 c = *(const f32x4*)(qr + kf * 32 + 4);
      bf16x8 t;
      t[0]=(__bf16)(a[0]*QSC); t[1]=(__bf16)(a[1]*QSC); t[2]=(__bf16)(a[2]*QSC); t[3]=(__bf16)(a[3]*QSC);
      t[4]=(__bf16)(c[0]*QSC); t[5]=(__bf16)(c[1]*QSC); t[6]=(__bf16)(c[2]*QSC); t[7]=(__bf16)(c[3]*QSC);
      qf[kf] = t;
    }
  }

  const float* kb = kg + (size_t)b * KLEN * DH;
  const float* vb = vg + (size_t)b * KLEN * DH;
  const int* mrow = maskg + b * KLEN;

  f32x4 kreg[8], va[4], vbr[4];

  auto load_tile = [&](int t) {
    const float* kt = kb + ((size_t)t * KT) * DH;
#pragma unroll
    for (int it = 0; it < 8; ++it) {
      int f = it * 256 + tid;
      kreg[it] = *(const f32x4*)(kt + (size_t)(f >> 5) * DH + (f & 31) * 4);
    }
    const float* vt = vb + ((size_t)t * KT) * DH;
#pragma unroll
    for (int it = 0; it < 4; ++it) {
      int u = it * 256 + tid;
      int m = u & 31, dc = (u >> 5) * 4;
      va[it]  = *(const f32x4*)(vt + (size_t)(2 * m) * DH + dc);
      vbr[it] = *(const f32x4*)(vt + (size_t)(2 * m + 1) * DH + dc);
    }
  };
  auto store_tile = [&]() {
#pragma unroll
    for (int it = 0; it < 8; ++it) {
      int f = it * 256 + tid;
      bf16x4 w;
      w[0]=(__bf16)kreg[it][0]; w[1]=(__bf16)kreg[it][1];
      w[2]=(__bf16)kreg[it][2]; w[3]=(__bf16)kreg[it][3];
      *(bf16x4*)&sK[f >> 5][(f & 31) * 4] = w;
    }
#pragma unroll
    for (int it = 0; it < 4; ++it) {
      int u = it * 256 + tid;
      int m = u & 31, dc = (u >> 5) * 4;
#pragma unroll
      for (int j = 0; j < 4; ++j) {
        bf16x2 p2;
        p2[0] = (__bf16)va[it][j];
        p2[1] = (__bf16)vbr[it][j];
        *(bf16x2*)&sVT[dc + j][2 * m] = p2;
      }
    }
  };

  f32x4 oacc[8];
#pragma unroll
  for (int i = 0; i < 8; ++i) oacc[i] = (f32x4){0.f, 0.f, 0.f, 0.f};
  float mi[4] = {-INFINITY, -INFINITY, -INFINITY, -INFINITY};
  float li[4] = {0.f, 0.f, 0.f, 0.f};

  load_tile(0); store_tile(); __syncthreads();

  for (int t = 0; t < (KLEN / KT); ++t) {
    const bool more = (t + 1 < (KLEN / KT));
    if (more) load_tile(t + 1);

    f32x4 sa[4];
#pragma unroll
    for (int f = 0; f < 4; ++f) sa[f] = (f32x4){0.f, 0.f, 0.f, 0.f};
#pragma unroll
    for (int kf = 0; kf < 4; ++kf)
#pragma unroll
      for (int f = 0; f < 4; ++f) {
        bf16x8 bk = *(const bf16x8*)&sK[f * 16 + lc][kf * 32 + qd * 8];
        sa[f] = __builtin_amdgcn_mfma_f32_16x16x32_bf16(qf[kf], bk, sa[f], 0, 0, 0);
      }

    const int kv0 = t * KT;
#pragma unroll
    for (int f = 0; f < 4; ++f) {
      const bool keep = mrow[kv0 + f * 16 + lc] != 0;
#pragma unroll
      for (int r = 0; r < 4; ++r) sa[f][r] = keep ? sa[f][r] : NEGV;
    }

    float rm[4], alpha[4], rs[4];
#pragma unroll
    for (int r = 0; r < 4; ++r)
      rm[r] = fmaxf(fmaxf(sa[0][r], sa[1][r]), fmaxf(sa[2][r], sa[3][r]));
#pragma unroll
    for (int sh = 0; sh < 4; ++sh) {
      const int off = 1 << sh;
#pragma unroll
      for (int r = 0; r < 4; ++r) rm[r] = fmaxf(rm[r], __shfl_xor(rm[r], off, 64));
    }
#pragma unroll
    for (int r = 0; r < 4; ++r) {
      float mn = fmaxf(mi[r], rm[r]);
      alpha[r] = __builtin_amdgcn_exp2f(mi[r] - mn);
      mi[r] = mn; rs[r] = 0.f;
    }
#pragma unroll
    for (int f = 0; f < 4; ++f)
#pragma unroll
      for (int r = 0; r < 4; ++r) {
        float p = __builtin_amdgcn_exp2f(sa[f][r] - mi[r]);
        sa[f][r] = p; rs[r] += p;
      }
#pragma unroll
    for (int sh = 0; sh < 4; ++sh) {
      const int off = 1 << sh;
#pragma unroll
      for (int r = 0; r < 4; ++r) rs[r] += __shfl_xor(rs[r], off, 64);
    }
#pragma unroll
    for (int r = 0; r < 4; ++r) li[r] = li[r] * alpha[r] + rs[r];

#pragma unroll
    for (int f = 0; f < 4; ++f)
#pragma unroll
      for (int r = 0; r < 4; ++r)
        sP[wv][qd * 4 + r][f * 16 + lc] = (__bf16)sa[f][r];
#pragma unroll
    for (int nt = 0; nt < 8; ++nt)
#pragma unroll
      for (int r = 0; r < 4; ++r) oacc[nt][r] *= alpha[r];

#pragma unroll
    for (int kp = 0; kp < 2; ++kp) {
      bf16x8 ap = *(const bf16x8*)&sP[wv][lc][kp * 32 + qd * 8];
#pragma unroll
      for (int nt = 0; nt < 8; ++nt) {
        bf16x8 bv = *(const bf16x8*)&sVT[nt * 16 + lc][kp * 32 + qd * 8];
        oacc[nt] = __builtin_amdgcn_mfma_f32_16x16x32_bf16(ap, bv, oacc[nt], 0, 0, 0);
      }
    }

    __syncthreads();
    if (more) store_tile();
    __syncthreads();
  }

  float inv[4];
#pragma unroll
  for (int r = 0; r < 4; ++r) inv[r] = 1.0f / li[r];
  float* orow = outg + ((size_t)(b * QL + qw)) * DH;
#pragma unroll
  for (int nt = 0; nt < 8; ++nt)
#pragma unroll
    for (int r = 0; r < 4; ++r)
      orow[(size_t)(qd * 4 + r) * DH + nt * 16 + lc] = oacc[nt][r] * inv[r];
}

extern "C" void kernel_launch(void* const* d_in, const int* in_sizes, int n_in,
                              void* d_out, int out_size, void* d_ws, size_t ws_size,
                              hipStream_t stream) {
  (void)in_sizes; (void)n_in; (void)out_size;
  const float* q = (const float*)d_in[0];
  const float* k = (const float*)d_in[1];
  const float* v = (const float*)d_in[2];
  const int* mask = (const int*)d_in[3];
  float* out = (float*)d_out;

  const size_t kv_elems = (size_t)BZ * KLEN * DH;  // per tensor (4 MiB as bf16)
  if (ws_size >= 2 * kv_elems * sizeof(__bf16)) {
    __bf16* khat = (__bf16*)d_ws;
    __bf16* vhat = khat + kv_elems;
    prep_kv<<<dim3(256), dim3(512), 0, stream>>>(k, v, khat, vhat);
    fattn4<<<dim3(512), dim3(256), 0, stream>>>(khat, vhat, q, mask, out);
  } else {
    fattn_mono<<<dim3(BZ * (QL / 64)), dim3(256), 0, stream>>>(q, k, v, mask, out);
  }
}